// Round 3
// baseline (2798.251 us; speedup 1.0000x reference)
//
#include <hip/hip_runtime.h>

// LSTM: B=1024, T=128, I=128, H=1024, O=64
// R2: (a) MFMA proj with hi/lo-split bf16 w_fc (45us -> ~5us, fp32-grade acc)
//     (b) double-buffered LDS in lstm_step: stage(ks+1) issued before
//         compute(ks), so the per-iteration vmcnt(0) barrier drain overlaps
//         with MFMA+ds_read of the current tile.
// Carried: XOR-swizzled LDS (bank-conflict-free ds_read_b128), 64x128 tiles,
// 2 blocks/CU, gate-interleaved W rows -> in-lane LSTM epilogue.

#define B_DIM 1024
#define H_DIM 1024
#define I_DIM 128
#define T_DIM 128
#define XROW  (T_DIM * I_DIM)   // 16384
#define KDIM  (I_DIM + H_DIM)   // 1152
#define GDIM  (4 * H_DIM)       // 4096
#define O_DIM 64

typedef float f32x4 __attribute__((ext_vector_type(4)));
typedef short bf16x8 __attribute__((ext_vector_type(8)));
typedef unsigned short u16x8 __attribute__((ext_vector_type(8)));

__device__ __forceinline__ unsigned short f2bf(float f) {
    union { float f; unsigned int u; } v; v.f = f;
    unsigned int r = v.u + 0x7fffu + ((v.u >> 16) & 1u);  // RNE
    return (unsigned short)(r >> 16);
}
__device__ __forceinline__ float bf2f(unsigned short b) {
    union { unsigned int u; float f; } v; v.u = ((unsigned int)b) << 16;
    return v.f;
}
__device__ __forceinline__ float sigm(float x) { return 1.f / (1.f + __expf(-x)); }
__device__ __forceinline__ float tanh_fast(float x) { return 2.f / (1.f + __expf(-2.f * x)) - 1.f; }

// ---- prep: fp32 x -> bf16 ----
__global__ void conv_x(const float* __restrict__ x, unsigned short* __restrict__ xb) {
    size_t i = ((size_t)blockIdx.x * 256 + threadIdx.x) * 8;
    float4 v0 = *(const float4*)(x + i);
    float4 v1 = *(const float4*)(x + i + 4);
    u16x8 o;
    o[0] = f2bf(v0.x); o[1] = f2bf(v0.y); o[2] = f2bf(v0.z); o[3] = f2bf(v0.w);
    o[4] = f2bf(v1.x); o[5] = f2bf(v1.y); o[6] = f2bf(v1.z); o[7] = f2bf(v1.w);
    *(u16x8*)(xb + i) = o;
}

// ---- prep: gate-interleaved W'' [4096 x 1152] bf16 + combined bias ----
// row r: nb=r>>7, q=r&127, wh=q>>6, w=q&63, gate=w>>4, jl=w&15
// orig gate row = gate*1024 + nb*32 + wh*16 + jl
__global__ void build_w(const float* __restrict__ w_ih, const float* __restrict__ w_hh,
                        const float* __restrict__ b_ih, const float* __restrict__ b_hh,
                        unsigned short* __restrict__ W, float* __restrict__ bias) {
    int r = blockIdx.x;
    int nb = r >> 7, q = r & 127;
    int wh = q >> 6, w = q & 63;
    int gate = w >> 4, jl = w & 15;
    int orig = gate * 1024 + nb * 32 + wh * 16 + jl;
    for (int k = threadIdx.x; k < KDIM; k += 256) {
        float v = (k < I_DIM) ? w_ih[(size_t)orig * I_DIM + k]
                              : w_hh[(size_t)orig * H_DIM + (k - I_DIM)];
        W[(size_t)r * KDIM + k] = f2bf(v);
    }
    if (threadIdx.x == 0) bias[r] = b_ih[orig] + b_hh[orig];
}

// ---- prep: w_fc fp32 -> hi/lo bf16 pair (two-term compensated split) ----
__global__ void conv_wfc(const float* __restrict__ w_fc,
                         unsigned short* __restrict__ whi,
                         unsigned short* __restrict__ wlo) {
    int i = blockIdx.x * 256 + threadIdx.x;  // 256 blocks -> 65536
    float v = w_fc[i];
    unsigned short h = f2bf(v);
    whi[i] = h;
    wlo[i] = f2bf(v - bf2f(h));
}

__global__ void zero_hc(unsigned short* __restrict__ h0, float* __restrict__ c) {
    int idx = blockIdx.x * 256 + threadIdx.x;
    h0[idx] = 0;
    c[idx] = 0.f;
}

// ---- per-timestep: 64x128 tile GEMM + fused LSTM cell epilogue ----
// Double-buffered LDS; XOR-swizzled layout (phys group = logical ^ (row&7)).
__global__ __launch_bounds__(256, 2)
void lstm_step(const unsigned short* __restrict__ xb,
               const unsigned short* __restrict__ W,
               const float* __restrict__ bias,
               const unsigned short* __restrict__ h_in,
               unsigned short* __restrict__ h_out,
               float* __restrict__ c_st,
               int t) {
    __shared__ __align__(16) unsigned short As[2][64 * 64];
    __shared__ __align__(16) unsigned short Bs[2][128 * 64];
    const int tid  = threadIdx.x;
    const int wv   = tid >> 6, lane = tid & 63;
    const int wm   = wv >> 1, wn = wv & 1;      // 2x2 wave grid over 64x128
    const int quad = lane >> 4, l16 = lane & 15;
    const int l7   = l16 & 7;
    const int nb   = blockIdx.x, mb = blockIdx.y;

    f32x4 acc[2][4];
#pragma unroll
    for (int i = 0; i < 2; i++)
#pragma unroll
        for (int j = 0; j < 4; j++) acc[i][j] = f32x4{0.f, 0.f, 0.f, 0.f};

    const int arow = lane >> 3;              // 0..7: row within 8-row chunk
    const int ag   = lane & 7;               // physical 16B group this lane fills
    const int colperm = ((ag ^ arow) << 3);  // swizzled source column (bf16 units)

    // row bases (wave-uniform) for staging
    const int arow0 = wv * 16;   // A: 2 chunks of 8 rows
    const int brow0 = wv * 32;   // B: 4 chunks of 8 rows

#define ISSUE_STAGE(ks_, buf_)                                                     \
    do {                                                                           \
        const int kt_ = (ks_) * 64;                                                \
        _Pragma("unroll")                                                          \
        for (int c4 = 0; c4 < 2; ++c4) {                                           \
            const int row0 = arow0 + c4 * 8;                                       \
            const int row  = row0 + arow;                                          \
            const unsigned short* srcA =                                           \
                (kt_ < I_DIM)                                                      \
                    ? xb   + (size_t)(mb * 64 + row) * XROW + t * I_DIM + kt_ + colperm \
                    : h_in + (size_t)(mb * 64 + row) * H_DIM + (kt_ - I_DIM) + colperm; \
            __builtin_amdgcn_global_load_lds(                                      \
                (const __attribute__((address_space(1))) void*)srcA,               \
                (__attribute__((address_space(3))) void*)(&As[buf_][row0 * 64]),   \
                16, 0, 0);                                                         \
        }                                                                          \
        _Pragma("unroll")                                                          \
        for (int c4 = 0; c4 < 4; ++c4) {                                           \
            const int row0 = brow0 + c4 * 8;                                       \
            const int row  = row0 + arow;                                          \
            const unsigned short* srcB =                                           \
                W + (size_t)(nb * 128 + row) * KDIM + kt_ + colperm;               \
            __builtin_amdgcn_global_load_lds(                                      \
                (const __attribute__((address_space(1))) void*)srcB,               \
                (__attribute__((address_space(3))) void*)(&Bs[buf_][row0 * 64]),   \
                16, 0, 0);                                                         \
        }                                                                          \
    } while (0)

    ISSUE_STAGE(0, 0);

    for (int ks = 0; ks < 18; ++ks) {
        const int cur = ks & 1;
        __syncthreads();                       // drains vmcnt: stage(ks) complete
        if (ks < 17) ISSUE_STAGE(ks + 1, cur ^ 1);
#pragma unroll
        for (int kk = 0; kk < 64; kk += 32) {
            const int gb = kk >> 3;  // logical group base: 0 or 4
            bf16x8 af[2], bfr[4];
#pragma unroll
            for (int mi = 0; mi < 2; mi++) {
                const int r = wm * 32 + mi * 16 + l16;
                af[mi] = *(const bf16x8*)&As[cur][r * 64 + (((gb + quad) ^ l7) << 3)];
            }
#pragma unroll
            for (int ni = 0; ni < 4; ni++) {
                const int r = wn * 64 + ni * 16 + l16;
                bfr[ni] = *(const bf16x8*)&Bs[cur][r * 64 + (((gb + quad) ^ l7) << 3)];
            }
#pragma unroll
            for (int mi = 0; mi < 2; mi++)
#pragma unroll
                for (int ni = 0; ni < 4; ni++)
                    acc[mi][ni] = __builtin_amdgcn_mfma_f32_16x16x32_bf16(
                        af[mi], bfr[ni], acc[mi][ni], 0, 0, 0);
        }
    }
#undef ISSUE_STAGE

    // epilogue: ni == gate (0:i 1:f 2:g 3:o), fully in-lane
    const int j  = nb * 32 + wn * 16 + l16;
    const int bb = nb * 128 + wn * 64 + l16;
    const float bi  = bias[bb +  0];
    const float bf_ = bias[bb + 16];
    const float bg  = bias[bb + 32];
    const float bo  = bias[bb + 48];
#pragma unroll
    for (int mi = 0; mi < 2; mi++) {
#pragma unroll
        for (int r = 0; r < 4; r++) {
            const int brow = mb * 64 + wm * 32 + mi * 16 + quad * 4 + r;
            const float gi = acc[mi][0][r] + bi;
            const float gf = acc[mi][1][r] + bf_;
            const float gg = acc[mi][2][r] + bg;
            const float go = acc[mi][3][r] + bo;
            const size_t idx = (size_t)brow * H_DIM + j;
            const float cn = sigm(gf) * c_st[idx] + sigm(gi) * tanh_fast(gg);
            c_st[idx] = cn;
            h_out[idx] = f2bf(sigm(go) * tanh_fast(cn));
        }
    }
}

// ---- final projection via MFMA: out[b,o] = h[b,:].w_fc[o,:] + b_fc ----
// w_fc as hi+lo bf16 pair -> fp32-grade accuracy. M=1024, N=64, K=1024.
__global__ __launch_bounds__(256, 1)
void proj_mfma(const unsigned short* __restrict__ h,
               const unsigned short* __restrict__ whi,
               const unsigned short* __restrict__ wlo,
               const float* __restrict__ b_fc,
               float* __restrict__ out) {
    const int wm = threadIdx.x >> 6, lane = threadIdx.x & 63;
    const int quad = lane >> 4, l16 = lane & 15;
    const int m0 = blockIdx.x * 64 + wm * 16;

    f32x4 acc[4];
#pragma unroll
    for (int ni = 0; ni < 4; ni++) acc[ni] = f32x4{0.f, 0.f, 0.f, 0.f};

    for (int k0 = 0; k0 < H_DIM; k0 += 32) {
        bf16x8 a = *(const bf16x8*)&h[(size_t)(m0 + l16) * H_DIM + k0 + quad * 8];
#pragma unroll
        for (int ni = 0; ni < 4; ni++) {
            const size_t wi = (size_t)(ni * 16 + l16) * H_DIM + k0 + quad * 8;
            bf16x8 bh = *(const bf16x8*)&whi[wi];
            bf16x8 bl = *(const bf16x8*)&wlo[wi];
            acc[ni] = __builtin_amdgcn_mfma_f32_16x16x32_bf16(a, bh, acc[ni], 0, 0, 0);
            acc[ni] = __builtin_amdgcn_mfma_f32_16x16x32_bf16(a, bl, acc[ni], 0, 0, 0);
        }
    }
#pragma unroll
    for (int ni = 0; ni < 4; ni++) {
        const float bfc = b_fc[ni * 16 + l16];
#pragma unroll
        for (int r = 0; r < 4; r++) {
            out[(size_t)(m0 + quad * 4 + r) * O_DIM + ni * 16 + l16] = acc[ni][r] + bfc;
        }
    }
}

extern "C" void kernel_launch(void* const* d_in, const int* in_sizes, int n_in,
                              void* d_out, int out_size, void* d_ws, size_t ws_size,
                              hipStream_t stream) {
    const float* x    = (const float*)d_in[0];
    const float* w_ih = (const float*)d_in[1];
    const float* w_hh = (const float*)d_in[2];
    const float* b_ih = (const float*)d_in[3];
    const float* b_hh = (const float*)d_in[4];
    const float* w_fc = (const float*)d_in[5];
    const float* b_fc = (const float*)d_in[6];
    float* out = (float*)d_out;

    char* ws = (char*)d_ws;
    size_t off = 0;
    unsigned short* xb  = (unsigned short*)(ws + off); off += (size_t)B_DIM * XROW * 2;
    unsigned short* W   = (unsigned short*)(ws + off); off += (size_t)GDIM * KDIM * 2;
    float* bias         = (float*)(ws + off);          off += (size_t)GDIM * 4;
    unsigned short* h0  = (unsigned short*)(ws + off); off += (size_t)B_DIM * H_DIM * 2;
    unsigned short* h1  = (unsigned short*)(ws + off); off += (size_t)B_DIM * H_DIM * 2;
    float* c            = (float*)(ws + off);          off += (size_t)B_DIM * H_DIM * 4;
    unsigned short* whi = (unsigned short*)(ws + off); off += (size_t)O_DIM * H_DIM * 2;
    unsigned short* wlo = (unsigned short*)(ws + off); off += (size_t)O_DIM * H_DIM * 2;

    conv_x<<<8192, 256, 0, stream>>>(x, xb);
    build_w<<<GDIM, 256, 0, stream>>>(w_ih, w_hh, b_ih, b_hh, W, bias);
    conv_wfc<<<256, 256, 0, stream>>>(w_fc, whi, wlo);
    zero_hc<<<4096, 256, 0, stream>>>(h0, c);

    for (int t = 0; t < T_DIM; ++t) {
        const unsigned short* hin = (t & 1) ? h1 : h0;
        unsigned short* hout      = (t & 1) ? h0 : h1;
        lstm_step<<<dim3(32, 16), 256, 0, stream>>>(xb, W, bias, hin, hout, c, t);
    }
    // t=127 wrote h0
    proj_mfma<<<16, 256, 0, stream>>>(h0, whi, wlo, b_fc, out);
}